// Round 1
// baseline (443.830 us; speedup 1.0000x reference)
//
#include <hip/hip_runtime.h>
#include <hip/hip_bf16.h>

// LengthRegulator: B=32, T=1024, D=384, MAX_LEN=8192
// out0: (B, MAX_LEN, D) f32 gather of x rows per searchsorted(cumsum(duration), frame, 'right')
// out1: (B,) mel_len = cumsum(duration)[:, -1], stored as float values in d_out tail.

#define LR_B 32
#define LR_T 1024
#define LR_D 384
#define LR_MAXLEN 8192
#define LR_D4 (LR_D / 4)            // 96 float4 per row
#define LR_N4 (LR_B * LR_MAXLEN * LR_D4)  // 25,165,824 float4 in out0

// Kernel A: per-batch inclusive scan of durations, emit mel_len (as float) and
// the frame->token index map (-1 for invalid frames) into workspace.
__global__ __launch_bounds__(LR_T) void lr_scan_scatter(
    const int* __restrict__ dur,     // (B, T)
    int* __restrict__ idx_ws,        // (B, MAX_LEN)
    float* __restrict__ mel_out)     // (B,) float-coded int
{
    const int b = blockIdx.x;
    const int t = threadIdx.x;
    __shared__ int csum[LR_T];

    csum[t] = dur[b * LR_T + t];
    __syncthreads();

    // Hillis-Steele inclusive scan, 10 steps
    #pragma unroll
    for (int off = 1; off < LR_T; off <<= 1) {
        int v = csum[t];
        int add = (t >= off) ? csum[t - off] : 0;
        __syncthreads();
        csum[t] = v + add;
        __syncthreads();
    }

    const int total = csum[LR_T - 1];   // mel_len, <= 7*1024 < MAX_LEN
    if (t == 0) mel_out[b] = (float)total;

    // Scatter: frames [csum[t-1], csum[t]) belong to token t (duration <= 7)
    int end = csum[t];
    int start = (t == 0) ? 0 : csum[t - 1];
    int* row = idx_ws + b * LR_MAXLEN;
    for (int f = start; f < end; ++f) row[f] = t;

    // Invalid frames -> -1
    for (int f = total + t; f < LR_MAXLEN; f += LR_T) row[f] = -1;
}

// Kernel B: one float4 of out0 per thread.
__global__ __launch_bounds__(256) void lr_gather(
    const float4* __restrict__ x,    // (B, T, D4)
    const int* __restrict__ idx_ws,  // (B, MAX_LEN)
    float4* __restrict__ out)        // (B, MAX_LEN, D4)
{
    const int g = blockIdx.x * 256 + threadIdx.x;   // < LR_N4 exactly
    const int frame = g / LR_D4;                    // magic-mul div by 96
    const int e = g - frame * LR_D4;
    const int b = frame >> 13;                      // / MAX_LEN
    const int idx = idx_ws[frame];

    float4 v = make_float4(0.f, 0.f, 0.f, 0.f);
    if (idx >= 0) {
        v = x[(b * LR_T + idx) * LR_D4 + e];
    }
    out[g] = v;
}

extern "C" void kernel_launch(void* const* d_in, const int* in_sizes, int n_in,
                              void* d_out, int out_size, void* d_ws, size_t ws_size,
                              hipStream_t stream) {
    const float* x   = (const float*)d_in[0];
    const int*   dur = (const int*)d_in[1];
    // d_in[2] = max_len (scalar on device) -- constant 8192 for this problem.

    float* out0 = (float*)d_out;                          // (B, MAX_LEN, D)
    float* mel  = out0 + (size_t)LR_B * LR_MAXLEN * LR_D; // (B,) tail
    int*   idx_ws = (int*)d_ws;                           // B*MAX_LEN ints = 1 MB

    lr_scan_scatter<<<LR_B, LR_T, 0, stream>>>(dur, idx_ws, mel);

    const int n_blocks = LR_N4 / 256;                     // 98304, exact
    lr_gather<<<n_blocks, 256, 0, stream>>>(
        (const float4*)x, idx_ws, (float4*)out0);
}

// Round 3
// 437.571 us; speedup vs baseline: 1.0143x; 1.0143x over previous
//
#include <hip/hip_runtime.h>
#include <hip/hip_bf16.h>

// LengthRegulator: B=32, T=1024, D=384, MAX_LEN=8192
// out0: (B, MAX_LEN, D) f32 gather of x rows per searchsorted(cumsum(duration), frame, 'right')
// out1: (B,) mel_len = cumsum(duration)[:, -1], stored as float values in d_out tail.

#define LR_B 32
#define LR_T 1024
#define LR_D 384
#define LR_MAXLEN 8192
#define LR_D4 (LR_D / 4)                  // 96 float4 per row
#define LR_N4 (LR_B * LR_MAXLEN * LR_D4)  // 25,165,824 float4 in out0
#define LR_UNROLL 8

typedef float fx4 __attribute__((ext_vector_type(4)));  // native vec: nontemporal-ok

// Kernel A: per-batch inclusive scan of durations via wave shuffles (2 barriers
// total). Emits mel_len (float-coded) and a frame -> source-offset table:
//   src_ws[b*MAX_LEN + f] = (b*T + token)*D4   for valid frames
//                         = -1                  for frames >= mel_len
__global__ __launch_bounds__(LR_T) void lr_scan_scatter(
    const int* __restrict__ dur,     // (B, T)
    int* __restrict__ src_ws,        // (B, MAX_LEN)
    float* __restrict__ mel_out)     // (B,) float-coded int
{
    const int b = blockIdx.x;
    const int t = threadIdx.x;
    const int lane = t & 63;
    const int wave = t >> 6;         // 16 waves

    const int d = dur[b * LR_T + t];

    // Inclusive scan within the wave (6 shuffle steps, no barriers)
    int v = d;
    #pragma unroll
    for (int off = 1; off < 64; off <<= 1) {
        int n = __shfl_up(v, off, 64);
        if (lane >= off) v += n;
    }

    __shared__ int wsum[16];
    __shared__ int woff[16];
    if (lane == 63) wsum[wave] = v;
    __syncthreads();

    // Scan the 16 wave sums inside wave 0
    if (wave == 0 && lane < 16) {
        int s = wsum[lane];
        #pragma unroll
        for (int off = 1; off < 16; off <<= 1) {
            int n = __shfl_up(s, off, 64);
            if (lane >= off) s += n;
        }
        woff[lane] = s;              // inclusive scan of wave sums
    }
    __syncthreads();

    const int base  = (wave == 0) ? 0 : woff[wave - 1];
    const int end   = base + v;      // inclusive csum at token t
    const int start = end - d;
    const int total = woff[15];      // mel_len, <= 7*1024 < MAX_LEN

    if (t == 0) mel_out[b] = (float)total;

    int* row = src_ws + b * LR_MAXLEN;
    const int src_off = (b * LR_T + t) * LR_D4;   // float4 offset of token row
    for (int f = start; f < end; ++f) row[f] = src_off;   // <= 7 iterations
    for (int f = total + t; f < LR_MAXLEN; f += LR_T) row[f] = -1;
}

// Kernel B: LR_UNROLL independent float4 copies per thread; nontemporal
// stores keep the 402 MB write stream out of L2 so x (48 MB, reused ~3.5x)
// stays cached.
__global__ __launch_bounds__(256) void lr_gather(
    const fx4* __restrict__ x,       // (B, T, D4)
    const int* __restrict__ src_ws,  // (B, MAX_LEN)
    fx4* __restrict__ out)           // (B, MAX_LEN, D4)
{
    const unsigned base = blockIdx.x * (256u * LR_UNROLL) + threadIdx.x;
    #pragma unroll
    for (int u = 0; u < LR_UNROLL; ++u) {
        const unsigned g = base + u * 256u;          // < LR_N4 exactly
        const unsigned frame = g / LR_D4;            // magic-mul div by 96
        const unsigned e = g - frame * LR_D4;
        const int s = src_ws[frame];
        fx4 v = (fx4)(0.f, 0.f, 0.f, 0.f);
        if (s >= 0) v = x[(unsigned)s + e];
        __builtin_nontemporal_store(v, out + g);
    }
}

extern "C" void kernel_launch(void* const* d_in, const int* in_sizes, int n_in,
                              void* d_out, int out_size, void* d_ws, size_t ws_size,
                              hipStream_t stream) {
    const float* x   = (const float*)d_in[0];
    const int*   dur = (const int*)d_in[1];
    // d_in[2] = max_len (scalar on device) -- constant 8192 for this problem.

    float* out0 = (float*)d_out;                          // (B, MAX_LEN, D)
    float* mel  = out0 + (size_t)LR_B * LR_MAXLEN * LR_D; // (B,) tail
    int*   src_ws = (int*)d_ws;                           // B*MAX_LEN ints = 1 MB

    lr_scan_scatter<<<LR_B, LR_T, 0, stream>>>(dur, src_ws, mel);

    const int n_blocks = LR_N4 / (256 * LR_UNROLL);       // 12288, exact
    lr_gather<<<n_blocks, 256, 0, stream>>>(
        (const fx4*)x, src_ws, (fx4*)out0);
}